// Round 3
// baseline (83.579 us; speedup 1.0000x reference)
//
#include <hip/hip_runtime.h>

// OrdFilter: 5x5 reflect-pad window, mean of top-9. In/out fp32 (16,1,512,512).
//
// Column-sharing sorting-network scheme, 8 pixels per thread:
//   - 12 shared vertical 5-columns sorted once (optimal 9-CE sorter each)
//   - 6 adjacent-pair merges -> sorted-10 (inf-elided bitonic merge, 15 CE)
//   - 5 shared top9s (max-trick 9 maxes + valley sort 13 CE), each feeding
//     1-2 pixels; per pixel fold one leftover sorted column (5 maxes) + sum.
// ~88 VALU ops/pixel (vs 130 in the 4-px version, vs 360 brute force).
// LDS tile XOR-swizzled (f ^= ((f>>5)&1)<<2) so strip-of-8 float4 reads are
// 2-way (free) instead of 4-way bank conflicts.
// All arrays constant-indexed & fully unrolled -> VGPRs, no scratch.

#define H 512
#define W 512
#define BY 16            // output rows per block
#define TXD 16           // threads in x
#define SPX 8            // pixels per thread (x strip)
#define BW (TXD * SPX)   // 128 output cols per block
#define PAD 2
#define TILW (BW + 2 * PAD)   // 132
#define TILH (BY + 2 * PAD)   // 20
#define TILN (TILW * TILH)    // 2640

__device__ __forceinline__ void ce(float& a, float& b) {
    const float lo = fminf(a, b);
    const float hi = fmaxf(a, b);
    a = lo;
    b = hi;
}

// optimal 9-CE ascending 5-sorter (verified via zero-one principle)
__device__ __forceinline__ void sort5(float* a) {
    ce(a[0], a[1]); ce(a[3], a[4]);
    ce(a[2], a[4]); ce(a[2], a[3]);
    ce(a[1], a[4]); ce(a[0], a[3]);
    ce(a[0], a[2]); ce(a[1], a[3]);
    ce(a[1], a[2]);
}

// merge two ascending 5-seqs -> ascending S[10] (inf-elided bitonic merge-16)
__device__ __forceinline__ void merge55(const float A[5], const float B[5], float S[10]) {
    float t0 = A[3], u0 = B[4]; ce(t0, u0);
    float t1 = A[4], u1 = B[3]; ce(t1, u1);
    float L0 = A[0], L1 = A[1], L2 = A[2], L3 = t0, L4 = t1, L5 = B[2], L6 = B[1], L7 = B[0];
    ce(L0, L4); ce(L1, L5); ce(L2, L6); ce(L3, L7);
    ce(L0, L2); ce(L1, L3); ce(L4, L6); ce(L5, L7);
    ce(L0, L1); ce(L2, L3); ce(L4, L5); ce(L6, L7);
    ce(u0, u1);
    S[0] = L0; S[1] = L1; S[2] = L2; S[3] = L3;
    S[4] = L4; S[5] = L5; S[6] = L6; S[7] = L7;
    S[8] = u0; S[9] = u1;
}

// sorted (ascending) top-9 of two ascending 10-seqs: cross-max (valley) + sort
__device__ __forceinline__ void top9_sorted(const float A[10], const float B[10], float S[9]) {
    float d0 = fmaxf(A[1], B[9]);
    float d1 = fmaxf(A[2], B[8]);
    float d2 = fmaxf(A[3], B[7]);
    float d3 = fmaxf(A[4], B[6]);
    float d4 = fmaxf(A[5], B[5]);
    float d5 = fmaxf(A[6], B[4]);
    float d6 = fmaxf(A[7], B[3]);
    float d7 = fmaxf(A[8], B[2]);
    float d8 = fmaxf(A[9], B[1]);
    ce(d0, d8);  // d8 = global max; d0..d7 bitonic
    ce(d0, d4); ce(d1, d5); ce(d2, d6); ce(d3, d7);
    ce(d0, d2); ce(d1, d3); ce(d4, d6); ce(d5, d7);
    ce(d0, d1); ce(d2, d3); ce(d4, d5); ce(d6, d7);
    S[0] = d0; S[1] = d1; S[2] = d2; S[3] = d3;
    S[4] = d4; S[5] = d5; S[6] = d6; S[7] = d7; S[8] = d8;
}

// mean of top-9 of (S[9] asc ∪ C[5] asc) via the (9,5,k=9) cross-max
__device__ __forceinline__ float final_mean(const float S[9], const float C[5]) {
    const float s = fmaxf(S[0], C[4]) + fmaxf(S[1], C[3]) + fmaxf(S[2], C[2]) +
                    fmaxf(S[3], C[1]) + fmaxf(S[4], C[0]) + S[5] + S[6] + S[7] + S[8];
    return s * (1.0f / 9.0f);
}

__device__ __forceinline__ int swz(int f) { return f ^ (((f >> 5) & 1) << 2); }

__global__ __launch_bounds__(256) void ordfilter_kernel(
    const float* __restrict__ in, float* __restrict__ out) {
    __shared__ float tile[TILN];

    const int bx = blockIdx.x * BW;
    const int by = blockIdx.y * BY;
    const int b  = blockIdx.z;
    const float* __restrict__ src = in  + (size_t)b * H * W;
    float* __restrict__ dst       = out + (size_t)b * H * W;

    const int tx  = threadIdx.x;
    const int ty  = threadIdx.y;
    const int tid = ty * TXD + tx;

    // ---- stage reflect-padded swizzled tile (20x132) ----
    for (int idx = tid; idx < TILN; idx += 256) {
        const int ly = idx / TILW;
        const int lx = idx - ly * TILW;
        int gy = by + ly - PAD;
        int gx = bx + lx - PAD;
        gy = gy < 0 ? -gy : (gy >= H ? 2 * H - 2 - gy : gy);
        gx = gx < 0 ? -gx : (gx >= W ? 2 * W - 2 - gx : gx);
        tile[swz(idx)] = src[gy * W + gx];
    }
    __syncthreads();

    // ---- load 12 columns x 5 rows via swizzled float4 LDS reads ----
    float c[12][5];
    #pragma unroll
    for (int i = 0; i < 5; ++i) {
        const int u0 = (ty + i) * (TILW / 4) + tx * (SPX / 4);  // float4-unit index
        const float4 a  = *reinterpret_cast<const float4*>(&tile[4 * ( u0      ^ (( u0      >> 3) & 1))]);
        const float4 b4 = *reinterpret_cast<const float4*>(&tile[4 * ((u0 + 1) ^ (((u0 + 1) >> 3) & 1))]);
        const float4 d4 = *reinterpret_cast<const float4*>(&tile[4 * ((u0 + 2) ^ (((u0 + 2) >> 3) & 1))]);
        c[0][i] = a.x;  c[1][i] = a.y;  c[2][i]  = a.z;  c[3][i]  = a.w;
        c[4][i] = b4.x; c[5][i] = b4.y; c[6][i]  = b4.z; c[7][i]  = b4.w;
        c[8][i] = d4.x; c[9][i] = d4.y; c[10][i] = d4.z; c[11][i] = d4.w;
    }

    // ---- sort the 12 shared columns ----
    #pragma unroll
    for (int k = 0; k < 12; ++k) sort5(c[k]);

    // ---- pair merges -> 6 sorted-10s ----
    float E[6][10];
    #pragma unroll
    for (int t = 0; t < 6; ++t) merge55(c[2 * t], c[2 * t + 1], E[t]);

    // ---- 5 shared top9s; per-pixel fold of leftover column ----
    // px 2t   = E_t ∪ E_{t+1} ∪ col(2t+4)
    // px 2t+1 = E_{t+1} ∪ E_{t+2} ∪ col(2t+1)
    float r[8];
    #pragma unroll
    for (int t = 0; t < 5; ++t) {
        float D[9];
        top9_sorted(E[t], E[t + 1], D);
        if (t == 0) {
            r[0] = final_mean(D, c[4]);
        } else if (t == 4) {
            r[7] = final_mean(D, c[7]);
        } else {
            r[2 * t - 1] = final_mean(D, c[2 * t - 1]);
            r[2 * t]     = final_mean(D, c[2 * t + 4]);
        }
    }

    float* orow = &dst[(by + ty) * W + bx + tx * SPX];
    float4 o0; o0.x = r[0]; o0.y = r[1]; o0.z = r[2]; o0.w = r[3];
    float4 o1; o1.x = r[4]; o1.y = r[5]; o1.z = r[6]; o1.w = r[7];
    *reinterpret_cast<float4*>(orow)     = o0;
    *reinterpret_cast<float4*>(orow + 4) = o1;
}

extern "C" void kernel_launch(void* const* d_in, const int* in_sizes, int n_in,
                              void* d_out, int out_size, void* d_ws, size_t ws_size,
                              hipStream_t stream) {
    const float* in = (const float*)d_in[0];
    float* out      = (float*)d_out;
    dim3 grid(W / BW, H / BY, 16);  // 4 x 32 x 16 = 2048 blocks
    dim3 block(TXD, BY);            // 256 threads
    ordfilter_kernel<<<grid, block, 0, stream>>>(in, out);
}